// Round 1
// baseline (342.836 us; speedup 1.0000x reference)
//
#include <hip/hip_runtime.h>
#include <cstddef>

typedef _Float16 f16;
typedef _Float16 f16x8 __attribute__((ext_vector_type(8)));
typedef _Float16 f16x4 __attribute__((ext_vector_type(4)));
typedef float f32x4 __attribute__((ext_vector_type(4)));

// ---------------------------------------------------------------------------
// Transpose + convert: in f32 [K][N] row-major -> out f16 [N][K] row-major.
// ---------------------------------------------------------------------------
__global__ __launch_bounds__(256) void transpose_f32_to_f16(
    const float* __restrict__ in, f16* __restrict__ out, int K, int N) {
  __shared__ float t[32][33];
  int tx = threadIdx.x % 32, ty = threadIdx.x / 32;  // ty in 0..7
  int n0 = blockIdx.x * 32, k0 = blockIdx.y * 32;
#pragma unroll
  for (int i = 0; i < 32; i += 8)
    t[ty + i][tx] = in[(size_t)(k0 + ty + i) * N + n0 + tx];
  __syncthreads();
#pragma unroll
  for (int i = 0; i < 32; i += 8)
    out[(size_t)(n0 + ty + i) * K + k0 + tx] = (f16)t[tx][ty + i];
}

// ---------------------------------------------------------------------------
// GEMM: C[M][N] = A[M][K] @ W[K][N], where Bt = W^T stored f16 [N][K].
// A is float (converted to f16 while staging) or f16. C is f16 or float.
// 128x128 tile / block, 256 threads = 4 waves, each wave 64x64 via 4x4 of
// mfma_f32_16x16x32_f16, BK=64 (2 k-steps per stage).
// MFMA layouts (guide-verified): A: m=lane&15, k=quad*8+j; B: n=lane&15,
// k=quad*8+j; C/D: col=lane&15, row=quad*4+reg.
// ---------------------------------------------------------------------------
template <typename AT, typename CT>
__global__ __launch_bounds__(256) void gemm_wt(
    const AT* __restrict__ A, const f16* __restrict__ Bt, CT* __restrict__ C,
    int M, int N, int K) {
  constexpr int BM = 128, BN = 128, BK = 64, LDA = BK + 8;  // 72 f16 = 144B rows
  __shared__ f16 As[BM * LDA];
  __shared__ f16 Bs[BN * LDA];

  const int nb = N / BN;
  const int m0 = (blockIdx.x / nb) * BM;
  const int n0 = (blockIdx.x % nb) * BN;
  const int tid = threadIdx.x;
  const int w = tid / 64, lane = tid % 64;
  const int l16 = lane % 16, quad = lane / 16;
  const int wrow = (w / 2) * 64, wcol = (w % 2) * 64;

  f32x4 acc[4][4] = {};

  for (int k0 = 0; k0 < K; k0 += BK) {
    // ---- stage A tile [BM][BK] (convert f32->f16 if needed) ----
    if constexpr (sizeof(AT) == 4) {
#pragma unroll
      for (int i = 0; i < 8; i++) {
        int r = tid / 16 + i * 16;
        int c = (tid % 16) * 4;
        float4 v = *(const float4*)&A[(size_t)(m0 + r) * K + k0 + c];
        f16x4 h;
        h[0] = (f16)v.x; h[1] = (f16)v.y; h[2] = (f16)v.z; h[3] = (f16)v.w;
        *(f16x4*)&As[r * LDA + c] = h;
      }
    } else {
#pragma unroll
      for (int i = 0; i < 4; i++) {
        int r = tid / 8 + i * 32;
        int c = (tid % 8) * 8;
        *(f16x8*)&As[r * LDA + c] =
            *(const f16x8*)&A[(size_t)(m0 + r) * K + k0 + c];
      }
    }
    // ---- stage B tile: Bt rows n0..n0+127, cols k0..k0+63 ----
#pragma unroll
    for (int i = 0; i < 4; i++) {
      int r = tid / 8 + i * 32;
      int c = (tid % 8) * 8;
      *(f16x8*)&Bs[r * LDA + c] =
          *(const f16x8*)&Bt[(size_t)(n0 + r) * K + k0 + c];
    }
    __syncthreads();

    f16x8 af[4][2], bf[4][2];
#pragma unroll
    for (int mt = 0; mt < 4; mt++)
#pragma unroll
      for (int s = 0; s < 2; s++)
        af[mt][s] = *(const f16x8*)&As[(wrow + mt * 16 + l16) * LDA + s * 32 + quad * 8];
#pragma unroll
    for (int nt = 0; nt < 4; nt++)
#pragma unroll
      for (int s = 0; s < 2; s++)
        bf[nt][s] = *(const f16x8*)&Bs[(wcol + nt * 16 + l16) * LDA + s * 32 + quad * 8];

#pragma unroll
    for (int mt = 0; mt < 4; mt++)
#pragma unroll
      for (int nt = 0; nt < 4; nt++) {
        acc[mt][nt] = __builtin_amdgcn_mfma_f32_16x16x32_f16(af[mt][0], bf[nt][0], acc[mt][nt], 0, 0, 0);
        acc[mt][nt] = __builtin_amdgcn_mfma_f32_16x16x32_f16(af[mt][1], bf[nt][1], acc[mt][nt], 0, 0, 0);
      }
    __syncthreads();
  }

  // ---- epilogue ----
#pragma unroll
  for (int mt = 0; mt < 4; mt++)
#pragma unroll
    for (int nt = 0; nt < 4; nt++)
#pragma unroll
      for (int r = 0; r < 4; r++) {
        int row = m0 + wrow + mt * 16 + quad * 4 + r;
        int col = n0 + wcol + nt * 16 + l16;
        C[(size_t)row * N + col] = (CT)acc[mt][nt][r];
      }
}

// ---------------------------------------------------------------------------
// Flash attention: Q [4096][1024] f16, KV [4096][2048] f16 (K cols 0..1023,
// V cols 1024..2047). Out Yh [4096][1024] f16 (head-merged layout).
// Block = (q-tile of 64 rows, head, batch); 4 waves x 16 q-rows.
// scores = (q . k) * 8  (reference divides by SCALE = Dh^-0.5 = 1/8).
// ---------------------------------------------------------------------------
__global__ __launch_bounds__(256) void attn_kernel(
    const f16* __restrict__ Qh, const f16* __restrict__ KVh, f16* __restrict__ Yh) {
  constexpr int LD = 72;
  __shared__ f16 Ks[64 * LD];  // [kv][d]
  __shared__ f16 Vt[64 * LD];  // [d][kv]  (transposed for B-fragment reads)
  __shared__ f16 Ps[64 * LD];  // [q][kv]  C-layout -> A-layout round trip

  const int qt = blockIdx.x, h = blockIdx.y, b = blockIdx.z;
  const int tid = threadIdx.x;
  const int w = tid / 64, lane = tid % 64;
  const int l16 = lane % 16, quad = lane / 16;

  const size_t qrow0 = (size_t)b * 2048 + qt * 64;
  const size_t kvrow0 = (size_t)b * 2048;

  // Q fragments for this wave's 16 rows, held in registers for whole kernel.
  f16x8 qf[2];
#pragma unroll
  for (int s = 0; s < 2; s++)
    qf[s] = *(const f16x8*)&Qh[(qrow0 + w * 16 + l16) * 1024 + h * 64 + s * 32 + quad * 8];

  float m_run[4], l_run[4];
  f32x4 o_acc[4] = {};
#pragma unroll
  for (int r = 0; r < 4; r++) { m_run[r] = -1e30f; l_run[r] = 0.0f; }

  for (int t = 0; t < 2048 / 64; t++) {
    // ---- stage K tile [kv][d] ----
#pragma unroll
    for (int i = 0; i < 2; i++) {
      int r = tid / 8 + i * 32;
      int c = (tid % 8) * 8;
      *(f16x8*)&Ks[r * LD + c] =
          *(const f16x8*)&KVh[(kvrow0 + t * 64 + r) * 2048 + h * 64 + c];
    }
    // ---- stage V tile transposed [d][kv] ----
#pragma unroll
    for (int i = 0; i < 2; i++) {
      int kv = tid / 8 + i * 32;
      int d0 = (tid % 8) * 8;
      f16x8 v = *(const f16x8*)&KVh[(kvrow0 + t * 64 + kv) * 2048 + 1024 + h * 64 + d0];
#pragma unroll
      for (int j = 0; j < 8; j++) Vt[(d0 + j) * LD + kv] = v[j];
    }
    __syncthreads();

    // ---- S = Q @ K^T, scaled ----
    f32x4 sacc[4];
#pragma unroll
    for (int nt = 0; nt < 4; nt++) {
      f16x8 kf0 = *(const f16x8*)&Ks[(nt * 16 + l16) * LD + quad * 8];
      f16x8 kf1 = *(const f16x8*)&Ks[(nt * 16 + l16) * LD + 32 + quad * 8];
      f32x4 z = {0.0f, 0.0f, 0.0f, 0.0f};
      z = __builtin_amdgcn_mfma_f32_16x16x32_f16(qf[0], kf0, z, 0, 0, 0);
      z = __builtin_amdgcn_mfma_f32_16x16x32_f16(qf[1], kf1, z, 0, 0, 0);
      sacc[nt] = z * 8.0f;
    }

    // ---- online softmax (rows = quad*4 + r, cols spread over 16 lanes x 4 nt) ----
    float mnew[4], alpha[4];
#pragma unroll
    for (int r = 0; r < 4; r++) {
      float mx = fmaxf(fmaxf(sacc[0][r], sacc[1][r]), fmaxf(sacc[2][r], sacc[3][r]));
#pragma unroll
      for (int off = 1; off < 16; off <<= 1) mx = fmaxf(mx, __shfl_xor(mx, off, 64));
      mnew[r] = fmaxf(m_run[r], mx);
      alpha[r] = __expf(m_run[r] - mnew[r]);
      m_run[r] = mnew[r];
    }
#pragma unroll
    for (int nt = 0; nt < 4; nt++)
#pragma unroll
      for (int r = 0; r < 4; r++) {
        float p = __expf(sacc[nt][r] - mnew[r]);
        sacc[nt][r] = p;
        Ps[(w * 16 + quad * 4 + r) * LD + nt * 16 + l16] = (f16)p;
      }
#pragma unroll
    for (int r = 0; r < 4; r++) {
      float s = sacc[0][r] + sacc[1][r] + sacc[2][r] + sacc[3][r];
#pragma unroll
      for (int off = 1; off < 16; off <<= 1) s += __shfl_xor(s, off, 64);
      l_run[r] = l_run[r] * alpha[r] + s;
#pragma unroll
      for (int nt = 0; nt < 4; nt++) o_acc[nt][r] *= alpha[r];
    }
    __syncthreads();  // P writes visible cross-lane

    // ---- O += P @ V ----
    f16x8 pf0 = *(const f16x8*)&Ps[(w * 16 + l16) * LD + quad * 8];
    f16x8 pf1 = *(const f16x8*)&Ps[(w * 16 + l16) * LD + 32 + quad * 8];
#pragma unroll
    for (int nt = 0; nt < 4; nt++) {
      f16x8 vf0 = *(const f16x8*)&Vt[(nt * 16 + l16) * LD + quad * 8];
      f16x8 vf1 = *(const f16x8*)&Vt[(nt * 16 + l16) * LD + 32 + quad * 8];
      o_acc[nt] = __builtin_amdgcn_mfma_f32_16x16x32_f16(pf0, vf0, o_acc[nt], 0, 0, 0);
      o_acc[nt] = __builtin_amdgcn_mfma_f32_16x16x32_f16(pf1, vf1, o_acc[nt], 0, 0, 0);
    }
    __syncthreads();  // protect Ks/Vt/Ps before next stage
  }

  // ---- epilogue: O /= l, write Yh ----
#pragma unroll
  for (int r = 0; r < 4; r++) {
    float inv = 1.0f / l_run[r];
    size_t row = qrow0 + w * 16 + quad * 4 + r;
#pragma unroll
    for (int nt = 0; nt < 4; nt++)
      Yh[row * 1024 + h * 64 + nt * 16 + l16] = (f16)(o_acc[nt][r] * inv);
  }
}

// ---------------------------------------------------------------------------
extern "C" void kernel_launch(void* const* d_in, const int* in_sizes, int n_in,
                              void* d_out, int out_size, void* d_ws, size_t ws_size,
                              hipStream_t stream) {
  const float* x_q  = (const float*)d_in[0];
  const float* x_kv = (const float*)d_in[1];
  const float* W_q  = (const float*)d_in[2];
  const float* W_kv = (const float*)d_in[3];
  const float* W_p  = (const float*)d_in[4];
  float* out = (float*)d_out;

  // workspace layout (f16 elements): 40 MB total
  f16* Wq_t  = (f16*)d_ws;                       // [1024][1024]
  f16* Wkv_t = Wq_t  + (size_t)1024 * 1024;      // [2048][1024]
  f16* Wp_t  = Wkv_t + (size_t)2048 * 1024;      // [1024][1024]
  f16* Qh    = Wp_t  + (size_t)1024 * 1024;      // [4096][1024]
  f16* KVh   = Qh    + (size_t)4096 * 1024;      // [4096][2048]
  f16* Yh    = KVh   + (size_t)4096 * 2048;      // [4096][1024]

  transpose_f32_to_f16<<<dim3(32, 32), 256, 0, stream>>>(W_q,  Wq_t,  1024, 1024);
  transpose_f32_to_f16<<<dim3(64, 32), 256, 0, stream>>>(W_kv, Wkv_t, 1024, 2048);
  transpose_f32_to_f16<<<dim3(32, 32), 256, 0, stream>>>(W_p,  Wp_t,  1024, 1024);

  gemm_wt<float, f16><<<256, 256, 0, stream>>>(x_q,  Wq_t,  Qh,  4096, 1024, 1024);
  gemm_wt<float, f16><<<512, 256, 0, stream>>>(x_kv, Wkv_t, KVh, 4096, 2048, 1024);

  attn_kernel<<<dim3(32, 16, 2), 256, 0, stream>>>(Qh, KVh, Yh);

  gemm_wt<f16, float><<<256, 256, 0, stream>>>(Yh, Wp_t, out, 4096, 1024, 1024);
}

// Round 2
// 292.692 us; speedup vs baseline: 1.1713x; 1.1713x over previous
//
#include <hip/hip_runtime.h>
#include <cstddef>

typedef _Float16 f16;
typedef _Float16 f16x8 __attribute__((ext_vector_type(8)));
typedef _Float16 f16x4 __attribute__((ext_vector_type(4)));
typedef _Float16 f16x2 __attribute__((ext_vector_type(2)));
typedef float f32x4 __attribute__((ext_vector_type(4)));

__device__ inline float exp2_fast(float x) {
  float r;
  asm("v_exp_f32 %0, %1" : "=v"(r) : "v"(x));
  return r;
}

// ---------------------------------------------------------------------------
// Transpose + convert: in f32 [K][N] row-major -> out f16 [N][K] row-major.
// ---------------------------------------------------------------------------
__global__ __launch_bounds__(256) void transpose_f32_to_f16(
    const float* __restrict__ in, f16* __restrict__ out, int K, int N) {
  __shared__ float t[32][33];
  int tx = threadIdx.x % 32, ty = threadIdx.x / 32;  // ty in 0..7
  int n0 = blockIdx.x * 32, k0 = blockIdx.y * 32;
#pragma unroll
  for (int i = 0; i < 32; i += 8)
    t[ty + i][tx] = in[(size_t)(k0 + ty + i) * N + n0 + tx];
  __syncthreads();
#pragma unroll
  for (int i = 0; i < 32; i += 8)
    out[(size_t)(n0 + ty + i) * K + k0 + tx] = (f16)t[tx][ty + i];
}

// ---------------------------------------------------------------------------
// GEMM: C[M][N] = A[M][K] @ W[K][N], where Bt = W^T stored f16 [N][K].
// 128x128 tile / block, 256 threads = 4 waves, each wave 64x64 via 4x4 of
// mfma_f32_16x16x32_f16, BK=64.
// ---------------------------------------------------------------------------
template <typename AT, typename CT>
__global__ __launch_bounds__(256) void gemm_wt(
    const AT* __restrict__ A, const f16* __restrict__ Bt, CT* __restrict__ C,
    int M, int N, int K) {
  constexpr int BM = 128, BN = 128, BK = 64, LDA = BK + 8;
  __shared__ f16 As[BM * LDA];
  __shared__ f16 Bs[BN * LDA];

  const int nb = N / BN;
  const int m0 = (blockIdx.x / nb) * BM;
  const int n0 = (blockIdx.x % nb) * BN;
  const int tid = threadIdx.x;
  const int w = tid / 64, lane = tid % 64;
  const int l16 = lane % 16, quad = lane / 16;
  const int wrow = (w / 2) * 64, wcol = (w % 2) * 64;

  f32x4 acc[4][4] = {};

  for (int k0 = 0; k0 < K; k0 += BK) {
    if constexpr (sizeof(AT) == 4) {
#pragma unroll
      for (int i = 0; i < 8; i++) {
        int r = tid / 16 + i * 16;
        int c = (tid % 16) * 4;
        float4 v = *(const float4*)&A[(size_t)(m0 + r) * K + k0 + c];
        f16x4 h;
        h[0] = (f16)v.x; h[1] = (f16)v.y; h[2] = (f16)v.z; h[3] = (f16)v.w;
        *(f16x4*)&As[r * LDA + c] = h;
      }
    } else {
#pragma unroll
      for (int i = 0; i < 4; i++) {
        int r = tid / 8 + i * 32;
        int c = (tid % 8) * 8;
        *(f16x8*)&As[r * LDA + c] =
            *(const f16x8*)&A[(size_t)(m0 + r) * K + k0 + c];
      }
    }
#pragma unroll
    for (int i = 0; i < 4; i++) {
      int r = tid / 8 + i * 32;
      int c = (tid % 8) * 8;
      *(f16x8*)&Bs[r * LDA + c] =
          *(const f16x8*)&Bt[(size_t)(n0 + r) * K + k0 + c];
    }
    __syncthreads();

    f16x8 af[4][2], bf[4][2];
#pragma unroll
    for (int mt = 0; mt < 4; mt++)
#pragma unroll
      for (int s = 0; s < 2; s++)
        af[mt][s] = *(const f16x8*)&As[(wrow + mt * 16 + l16) * LDA + s * 32 + quad * 8];
#pragma unroll
    for (int nt = 0; nt < 4; nt++)
#pragma unroll
      for (int s = 0; s < 2; s++)
        bf[nt][s] = *(const f16x8*)&Bs[(wcol + nt * 16 + l16) * LDA + s * 32 + quad * 8];

#pragma unroll
    for (int mt = 0; mt < 4; mt++)
#pragma unroll
      for (int nt = 0; nt < 4; nt++) {
        acc[mt][nt] = __builtin_amdgcn_mfma_f32_16x16x32_f16(af[mt][0], bf[nt][0], acc[mt][nt], 0, 0, 0);
        acc[mt][nt] = __builtin_amdgcn_mfma_f32_16x16x32_f16(af[mt][1], bf[nt][1], acc[mt][nt], 0, 0, 0);
      }
    __syncthreads();
  }

#pragma unroll
  for (int mt = 0; mt < 4; mt++)
#pragma unroll
    for (int nt = 0; nt < 4; nt++)
#pragma unroll
      for (int r = 0; r < 4; r++) {
        int row = m0 + wrow + mt * 16 + quad * 4 + r;
        int col = n0 + wcol + nt * 16 + l16;
        C[(size_t)row * N + col] = (CT)acc[mt][nt][r];
      }
}

// ---------------------------------------------------------------------------
// Flash attention. Q [4096][1024] f16, KV [4096][2048] f16 (K cols 0..1023,
// V cols 1024..2047). Out Yh [4096][1024] f16.
// Block = (q-tile 64, head, batch); 4 waves x 16 q-rows; KV tile 64.
// Vt is stored XOR-swizzled: elem (d, kv) lives at
//   d*LD + ((((kv>>3) ^ ((d>>3)&7)) << 3) | (kv&7))
// -> paired f16x2 staging writes are bank-conflict-free; b128 reads stay
// 16B-aligned. Softmax runs in log2 domain (scale = 8*log2(e), raw v_exp).
// ---------------------------------------------------------------------------
__global__ __launch_bounds__(256) void attn_kernel(
    const f16* __restrict__ Qh, const f16* __restrict__ KVh, f16* __restrict__ Yh) {
  constexpr int LD = 72;
  __shared__ f16 Ks[64 * LD];  // [kv][d]
  __shared__ f16 Vt[64 * LD];  // swizzled [d][kv]
  __shared__ f16 Ps[64 * LD];  // [q][kv]

  const int qt = blockIdx.x, h = blockIdx.y, b = blockIdx.z;
  const int tid = threadIdx.x;
  const int w = tid / 64, lane = tid % 64;
  const int l16 = lane % 16, quad = lane / 16;

  const size_t qrow0 = (size_t)b * 2048 + qt * 64;
  const size_t kvrow0 = (size_t)b * 2048;

  f16x8 qf[2];
#pragma unroll
  for (int s = 0; s < 2; s++)
    qf[s] = *(const f16x8*)&Qh[(qrow0 + w * 16 + l16) * 1024 + h * 64 + s * 32 + quad * 8];

  constexpr float SC = 11.5415603f;  // 8 * log2(e): log2-domain logits
  float m_run[4], l_run[4];
  f32x4 o_acc[4] = {};
#pragma unroll
  for (int r = 0; r < 4; r++) { m_run[r] = -1e30f; l_run[r] = 0.0f; }

  // V staging mapping (whole tile in one pass): 2 kv-rows, 8 d per thread.
  const int vkv0 = (tid >> 3) * 2;       // 0,2,..,62
  const int vd0 = (tid & 7) * 8;         // 0,8,..,56
  const int vcol = ((((vkv0 >> 3) ^ (tid & 7)) << 3) | (vkv0 & 7));

  for (int t = 0; t < 2048 / 64; t++) {
    // ---- stage K tile [kv][d] ----
#pragma unroll
    for (int i = 0; i < 2; i++) {
      int r = tid / 8 + i * 32;
      int c = (tid % 8) * 8;
      *(f16x8*)&Ks[r * LD + c] =
          *(const f16x8*)&KVh[(kvrow0 + t * 64 + r) * 2048 + h * 64 + c];
    }
    // ---- stage V tile, swizzled transpose, paired b32 writes ----
    {
      const f16* vsrc = &KVh[(kvrow0 + t * 64 + vkv0) * 2048 + 1024 + h * 64 + vd0];
      f16x8 va = *(const f16x8*)vsrc;
      f16x8 vb = *(const f16x8*)(vsrc + 2048);
#pragma unroll
      for (int j = 0; j < 8; j++) {
        f16x2 p; p[0] = va[j]; p[1] = vb[j];
        *(f16x2*)&Vt[(vd0 + j) * LD + vcol] = p;
      }
    }
    __syncthreads();

    // ---- S = Q @ K^T (log2-domain scale) ----
    f32x4 sacc[4];
#pragma unroll
    for (int nt = 0; nt < 4; nt++) {
      f16x8 kf0 = *(const f16x8*)&Ks[(nt * 16 + l16) * LD + quad * 8];
      f16x8 kf1 = *(const f16x8*)&Ks[(nt * 16 + l16) * LD + 32 + quad * 8];
      f32x4 z = {0.0f, 0.0f, 0.0f, 0.0f};
      z = __builtin_amdgcn_mfma_f32_16x16x32_f16(qf[0], kf0, z, 0, 0, 0);
      z = __builtin_amdgcn_mfma_f32_16x16x32_f16(qf[1], kf1, z, 0, 0, 0);
      sacc[nt] = z * SC;
    }

    // ---- online softmax ----
    float mnew[4], alpha[4];
#pragma unroll
    for (int r = 0; r < 4; r++) {
      float mx = fmaxf(fmaxf(sacc[0][r], sacc[1][r]), fmaxf(sacc[2][r], sacc[3][r]));
#pragma unroll
      for (int off = 1; off < 16; off <<= 1) mx = fmaxf(mx, __shfl_xor(mx, off, 64));
      mnew[r] = fmaxf(m_run[r], mx);
      alpha[r] = exp2_fast(m_run[r] - mnew[r]);
      m_run[r] = mnew[r];
    }
#pragma unroll
    for (int nt = 0; nt < 4; nt++)
#pragma unroll
      for (int r = 0; r < 4; r++) {
        float p = exp2_fast(sacc[nt][r] - mnew[r]);
        sacc[nt][r] = p;
        Ps[(w * 16 + quad * 4 + r) * LD + nt * 16 + l16] = (f16)p;
      }
#pragma unroll
    for (int r = 0; r < 4; r++) {
      float s = sacc[0][r] + sacc[1][r] + sacc[2][r] + sacc[3][r];
#pragma unroll
      for (int off = 1; off < 16; off <<= 1) s += __shfl_xor(s, off, 64);
      l_run[r] = l_run[r] * alpha[r] + s;
#pragma unroll
      for (int nt = 0; nt < 4; nt++) o_acc[nt][r] *= alpha[r];
    }
    // NOTE: no barrier here — Ps rows [w*16, w*16+15] are written and read
    // only by wave w; intra-wave LDS RAW is ordered by lgkmcnt.

    // ---- O += P @ V ----
    f16x8 pf0 = *(const f16x8*)&Ps[(w * 16 + l16) * LD + quad * 8];
    f16x8 pf1 = *(const f16x8*)&Ps[(w * 16 + l16) * LD + 32 + quad * 8];
#pragma unroll
    for (int nt = 0; nt < 4; nt++) {
      const int drow = nt * 16 + l16;
      const int xv = (drow >> 3) & 7;
      f16x8 vf0 = *(const f16x8*)&Vt[drow * LD + ((quad ^ xv) << 3)];
      f16x8 vf1 = *(const f16x8*)&Vt[drow * LD + (((quad + 4) ^ xv) << 3)];
      o_acc[nt] = __builtin_amdgcn_mfma_f32_16x16x32_f16(pf0, vf0, o_acc[nt], 0, 0, 0);
      o_acc[nt] = __builtin_amdgcn_mfma_f32_16x16x32_f16(pf1, vf1, o_acc[nt], 0, 0, 0);
    }
    __syncthreads();  // protect Ks/Vt before next stage
  }

#pragma unroll
  for (int r = 0; r < 4; r++) {
    float inv = 1.0f / l_run[r];
    size_t row = qrow0 + w * 16 + quad * 4 + r;
#pragma unroll
    for (int nt = 0; nt < 4; nt++)
      Yh[row * 1024 + h * 64 + nt * 16 + l16] = (f16)(o_acc[nt][r] * inv);
  }
}

// ---------------------------------------------------------------------------
extern "C" void kernel_launch(void* const* d_in, const int* in_sizes, int n_in,
                              void* d_out, int out_size, void* d_ws, size_t ws_size,
                              hipStream_t stream) {
  const float* x_q  = (const float*)d_in[0];
  const float* x_kv = (const float*)d_in[1];
  const float* W_q  = (const float*)d_in[2];
  const float* W_kv = (const float*)d_in[3];
  const float* W_p  = (const float*)d_in[4];
  float* out = (float*)d_out;

  f16* Wq_t  = (f16*)d_ws;                       // [1024][1024]
  f16* Wkv_t = Wq_t  + (size_t)1024 * 1024;      // [2048][1024]
  f16* Wp_t  = Wkv_t + (size_t)2048 * 1024;      // [1024][1024]
  f16* Qh    = Wp_t  + (size_t)1024 * 1024;      // [4096][1024]
  f16* KVh   = Qh    + (size_t)4096 * 1024;      // [4096][2048]
  f16* Yh    = KVh   + (size_t)4096 * 2048;      // [4096][1024]

  transpose_f32_to_f16<<<dim3(32, 32), 256, 0, stream>>>(W_q,  Wq_t,  1024, 1024);
  transpose_f32_to_f16<<<dim3(64, 32), 256, 0, stream>>>(W_kv, Wkv_t, 1024, 2048);
  transpose_f32_to_f16<<<dim3(32, 32), 256, 0, stream>>>(W_p,  Wp_t,  1024, 1024);

  gemm_wt<float, f16><<<256, 256, 0, stream>>>(x_q,  Wq_t,  Qh,  4096, 1024, 1024);
  gemm_wt<float, f16><<<512, 256, 0, stream>>>(x_kv, Wkv_t, KVh, 4096, 2048, 1024);

  attn_kernel<<<dim3(32, 16, 2), 256, 0, stream>>>(Qh, KVh, Yh);

  gemm_wt<f16, float><<<256, 256, 0, stream>>>(Yh, Wp_t, out, 4096, 1024, 1024);
}